// Round 11
// baseline (1678.211 us; speedup 1.0000x reference)
//
#include <hip/hip_runtime.h>
#include <math.h>

#define DATA 64
#define WIDTH 256
#define BATCHN 512
#define TPTS 16
#define MAXSUB 8
#define NSAMP 2
#define NBLK (BATCHN / NSAMP)
#define NTHR 1024

#define RTOLc 1e-3f
#define ATOLc 1e-6f
#define SAFETYc 0.9f
#define FMINc 0.2f
#define FMAXc 10.0f

// Tsit5 tableau
#define A21 0.161f
#define A31 (-0.008480655492356989f)
#define A32 0.335480655492357f
#define A41 2.8971530571054935f
#define A42 (-6.359448489975075f)
#define A43 4.3622954328695815f
#define A51 5.325864828439257f
#define A52 (-11.748883564062828f)
#define A53 7.4955393428898365f
#define A54 (-0.09249506636175525f)
#define A61 5.86145544294642f
#define A62 (-12.92096931784711f)
#define A63 8.159367898576159f
#define A64 (-0.071584973281401f)
#define A65 (-0.028269050394068383f)
#define B1c 0.09646076681806523f
#define B2c 0.01f
#define B3c 0.4798896504144996f
#define B4c 1.379008574103742f
#define B5c (-3.290069515436081f)
#define B6c 2.324710524099774f
#define E1c (-0.001780011052226f)
#define E2c (-0.000816434459657f)
#define E3c 0.007880878010262f
#define E4c (-0.144711007173263f)
#define E5c 0.582357165452555f
#define E6c (-0.458082105929187f)
#define E7c 0.015151515151515152f

__device__ __forceinline__ float softplus_jax(float x) {
    // jax.nn.softplus(x) == max(x,0) + log1p(exp(-|x|))
    return fmaxf(x, 0.0f) + log1pf(expf(-fabsf(x)));
}

__device__ __forceinline__ float4 f4add(const float4 a, const float4 b) {
    float4 r; r.x = a.x + b.x; r.y = a.y + b.y; r.z = a.z + b.z; r.w = a.w + b.w; return r;
}

// NOTE (R7 lesson): macro parameter names must not collide with .x/.y/.z/.w.
// NOTE (R10 lesson): never pass a brace-block with top-level commas as a macro
// argument — the preprocessor splits on commas outside parentheses.
#define DOT4(ACC_, WQ_, XV_)                                                  \
    ACC_ = fmaf((WQ_).x, (XV_).x, ACC_); ACC_ = fmaf((WQ_).y, (XV_).y, ACC_); \
    ACC_ = fmaf((WQ_).z, (XV_).z, ACC_); ACC_ = fmaf((WQ_).w, (XV_).w, ACC_);

// A_.{x..w} += W_.{x..w} * XS_  (4 output rows, one broadcast input)
#define FMA4(A_, W_, XS_)                                                     \
    A_.x = fmaf((W_).x, (XS_), A_.x); A_.y = fmaf((W_).y, (XS_), A_.y);       \
    A_.z = fmaf((W_).z, (XS_), A_.z); A_.w = fmaf((W_).w, (XS_), A_.w);

#define F4MUL(D_, S_, V_)                                                     \
    D_.x = (S_)*(V_).x; D_.y = (S_)*(V_).y; D_.z = (S_)*(V_).z; D_.w = (S_)*(V_).w;
#define F4FMA(D_, S_, V_)                                                     \
    D_.x = fmaf((S_),(V_).x,D_.x); D_.y = fmaf((S_),(V_).y,D_.y);             \
    D_.z = fmaf((S_),(V_).z,D_.z); D_.w = fmaf((S_),(V_).w,D_.w);

// float4 views (rows are 256B-aligned)
#define PS2C(SM_, C_, CI_) (reinterpret_cast<const float4*>(s_ps2[SM_][C_])[CI_])
#define PS2SUM(SM_, CI_)                                                      \
    f4add(f4add(f4add(PS2C(SM_,0,CI_), PS2C(SM_,1,CI_)),                      \
                f4add(PS2C(SM_,2,CI_), PS2C(SM_,3,CI_))),                     \
          f4add(f4add(PS2C(SM_,4,CI_), PS2C(SM_,5,CI_)),                      \
                f4add(PS2C(SM_,6,CI_), PS2C(SM_,7,CI_))))
#define K4(SM_, J_, CI_) (reinterpret_cast<const float4*>(s_k[SM_][J_])[CI_])
#define Y4(SM_, CI_)     (reinterpret_cast<const float4*>(s_y[SM_])[CI_])

// ---- phase A tail: L0 FMA from x4[2] registers, store float4 partials ----
#define L0_FMA_STORE(X4_)                                                     \
    { float4 acc0 = {0,0,0,0};                                                \
      _Pragma("unroll")                                                       \
      for (int half = 0; half < 2; ++half) {                                  \
          const float4 xv = (X4_)[half];                                      \
          const int kb = c8 * 8 + half * 4;                                   \
          { const float4 wva = sW0p[kb+0][g]; FMA4(acc0, wva, xv.x) }         \
          { const float4 wvb = sW0p[kb+1][g]; FMA4(acc0, wvb, xv.y) }         \
          { const float4 wvc = sW0p[kb+2][g]; FMA4(acc0, wvc, xv.z) }         \
          { const float4 wvd = sW0p[kb+3][g]; FMA4(acc0, wvd, xv.w) }         \
      }                                                                       \
      s_ps4[smA][c8][g] = acc0; }                                             \
    __syncthreads();

// ---- phases B,C,D,E (identical for every stage) ----
#define FEVAL_BCDE()                                                          \
    if (t < 128) { /* B: h0 combine, float4 b128 reads, conflict-free */      \
        const int sB = t >> 6;                                                \
        const int gg = t & 63;                                                \
        const float4 acc = f4add(f4add(f4add(s_ps4[sB][0][gg], s_ps4[sB][1][gg]), \
                                       f4add(s_ps4[sB][2][gg], s_ps4[sB][3][gg])), \
                                 f4add(f4add(s_ps4[sB][4][gg], s_ps4[sB][5][gg]), \
                                       f4add(s_ps4[sB][6][gg], s_ps4[sB][7][gg]))); \
        s_h0[sB][gg]       = softplus_jax(acc.x + s_b0[gg]);                  \
        s_h0[sB][gg +  64] = softplus_jax(acc.y + s_b0[gg +  64]);            \
        s_h0[sB][gg + 128] = softplus_jax(acc.z + s_b0[gg + 128]);            \
        s_h0[sB][gg + 192] = softplus_jax(acc.w + s_b0[gg + 192]);            \
    }                                                                         \
    __syncthreads();                                                          \
    { /* C: L1, W1 in VGPRs, broadcast inputs, both samples */                \
        const float4* xx0 = reinterpret_cast<const float4*>(&s_h0[0][h * 64]);\
        const float4* xx1 = reinterpret_cast<const float4*>(&s_h0[1][h * 64]);\
        float a0 = 0.f;                                                       \
        float a1 = 0.f;                                                       \
        float c0 = 0.f;                                                       \
        float c1 = 0.f;                                                       \
        _Pragma("unroll")                                                     \
        for (int j = 0; j < 16; j += 2) {                                     \
            float4 u = xx0[j];                                                \
            float4 v = xx1[j];                                                \
            DOT4(a0, w1q[j], u); DOT4(a1, w1q[j], v);                         \
            float4 u2 = xx0[j + 1];                                           \
            float4 v2 = xx1[j + 1];                                           \
            DOT4(c0, w1q[j + 1], u2); DOT4(c1, w1q[j + 1], v2);               \
        }                                                                     \
        s_ps[0][h][r] = a0 + c0; s_ps[1][h][r] = a1 + c1;                     \
    }                                                                         \
    __syncthreads();                                                          \
    if (t < 512) { /* D: h1 combine */                                        \
        const int sD = t >> 8;                                                \
        const int rD = t & 255;                                               \
        s_h1[sD][rD] = softplus_jax(((s_ps[sD][0][rD] + s_ps[sD][1][rD])      \
                                   + (s_ps[sD][2][rD] + s_ps[sD][3][rD])) + s_b1[rD]); \
    }                                                                         \
    __syncthreads();                                                          \
    { /* E: L2, W2 from LDS (lane-consecutive), one sample per thread.        \
         c8==0 folds in b2 so PS2SUM/kv7 = full f including output bias. */   \
        const float4* xx = reinterpret_cast<const float4*>(&s_h1[smA][c8 * 32]); \
        float e0 = 0.f;                                                       \
        float f0 = 0.f;                                                       \
        _Pragma("unroll")                                                     \
        for (int j = 0; j < 8; ++j) {                                         \
            const float4 q = xx[j];                                           \
            const int kb = c8 * 32 + j * 4;                                   \
            e0 = fmaf(sW2T[kb + 0][g], q.x, e0);                              \
            e0 = fmaf(sW2T[kb + 1][g], q.y, e0);                              \
            f0 = fmaf(sW2T[kb + 2][g], q.z, f0);                              \
            f0 = fmaf(sW2T[kb + 3][g], q.w, f0);                              \
        }                                                                     \
        s_ps2[smA][c8][g] = (e0 + f0) + (c8 == 0 ? s_b2[g] : 0.0f);           \
    }                                                                         \
    __syncthreads();

__global__ __launch_bounds__(NTHR)
void ode_kernel(const float* __restrict__ ts, const float* __restrict__ y0,
                const float* __restrict__ W0, const float* __restrict__ b0,
                const float* __restrict__ W1, const float* __restrict__ b1,
                const float* __restrict__ W2, const float* __restrict__ b2,
                float* __restrict__ out)
{
    __shared__ __align__(16) float4 sW0p[DATA][64];       // 64 KB: [k][g] rows {g,+64,+128,+192}
    __shared__ __align__(16) float  sW2T[WIDTH][DATA];    // 64 KB: [k][g]
    __shared__ __align__(16) char   s_un[16384];          // 16 KB union: L0-f4 partials / L1 partials
    __shared__ __align__(16) float  s_ps2[NSAMP][8][DATA];   // 4 KB: L2 partials (8-way)
    __shared__ __align__(16) float  s_h0[NSAMP][WIDTH];
    __shared__ __align__(16) float  s_h1[NSAMP][WIDTH];
    __shared__ __align__(16) float  s_y[NSAMP][DATA];
    __shared__ __align__(16) float  s_ynew[NSAMP][DATA];
    __shared__ __align__(16) float  s_k[NSAMP][6][DATA];  // k1..k6
    __shared__ float s_b0[WIDTH], s_b1[WIDTH], s_b2[DATA];
    __shared__ float s_ts[TPTS];
    __shared__ float s_err[NSAMP];

    float4 (*s_ps4)[8][64] = reinterpret_cast<float4 (*)[8][64]>(s_un); // [2][8][64] f4, A->B
    float  (*s_ps )[4][256] = reinterpret_cast<float (*)[4][256]>(s_un); // [2][4][256] f32, C->D

    const int t   = threadIdx.x;
    const int g   = t & 63;
    const int c8  = (t >> 6) & 7;   // k-chunk: L0 8-elem slice, L2 32-elem slice
    const int smA = t >> 9;         // sample for phases A/E
    const int r   = t & 255;        // L1 row
    const int h   = t >> 8;         // L1 k-quarter (0..3)
    const int b   = blockIdx.x;

    // ---- prologue (one-time) ----
    float4 w1q[16];   // W1 row r, k-slice [h*64,+64) — DIRECT contiguous loads (no pack)
    {
        const float4* p1 = reinterpret_cast<const float4*>(W1 + r * WIDTH + h * 64);
#pragma unroll
        for (int j = 0; j < 16; ++j) w1q[j] = p1[j];
    }
    for (int i = t; i < DATA * DATA; i += NTHR) {   // sW0p build
        const int kk = i >> 6, gg = i & 63;
        float4 w;
        w.x = W0[(gg      ) * DATA + kk];
        w.y = W0[(gg +  64) * DATA + kk];
        w.z = W0[(gg + 128) * DATA + kk];
        w.w = W0[(gg + 192) * DATA + kk];
        sW0p[kk][gg] = w;
    }
    for (int i = t; i < DATA * WIDTH; i += NTHR) {  // sW2T build (one-time; conflicts negligible)
        const int dd = i >> 8, kk = i & 255;
        sW2T[kk][dd] = W2[i];
    }
    if (t < WIDTH) { s_b0[t] = b0[t]; s_b1[t] = b1[t]; }
    if (t < DATA)  { s_b2[t] = b2[t]; }
    if (t < TPTS)  { s_ts[t] = ts[t]; }
    if (t < NSAMP * DATA) {
        const int s_ = t >> 6, d_ = t & 63;
        const float v = y0[(b * NSAMP + s_) * DATA + d_];
        s_y[s_][d_] = v;
        out[(size_t)(b * NSAMP + s_) * TPTS * DATA + d_] = v;
    }
    __syncthreads();

    float dtv0 = s_ts[1] - s_ts[0];
    float dtv1 = dtv0;
    bool havek1 = false;   // block-uniform

    for (int iv = 0; iv < TPTS - 1; ++iv) {
        const float t1v = s_ts[iv + 1];
        float tc0 = s_ts[iv], tc1 = tc0;

        for (int ss = 0; ss < MAXSUB; ++ss) {
            const float rem0 = t1v - tc0, rem1 = t1v - tc1;
            const bool done0 = rem0 <= 1e-6f, done1 = rem1 <= 1e-6f;
            if (done0 && done1) break;
            const float dtc0 = done0 ? dtv0 : fminf(dtv0, rem0);
            const float dtc1 = done1 ? dtv1 : fminf(dtv1, rem1);
            const float dtcS = (smA == 0) ? dtc0 : dtc1;

            // ---- k1 feval: only the very first substep of the solve (FSAL) ----
            if (!havek1) {
                float4 x4[2];
                x4[0] = Y4(smA, c8 * 2);
                x4[1] = Y4(smA, c8 * 2 + 1);
                L0_FMA_STORE(x4)
                FEVAL_BCDE()
                if (t < 32) {  // commit k1
                    const int s_ = t >> 4;
                    const int ci_ = t & 15;
                    reinterpret_cast<float4*>(s_k[s_][0])[ci_] = PS2SUM(s_, ci_);
                }
                __syncthreads();
                havek1 = true;
            }

            // ---- stage 2: x = y + dt*(A21*k1) ----
            {
                float4 x4[2];
#pragma unroll
                for (int hh = 0; hh < 2; ++hh) {
                    const int ci = c8 * 2 + hh;
                    const float4 k0 = K4(smA, 0, ci);
                    float4 acc; F4MUL(acc, A21, k0)
                    float4 xx = Y4(smA, ci); F4FMA(xx, dtcS, acc)
                    x4[hh] = xx;
                }
                L0_FMA_STORE(x4)
            }
            FEVAL_BCDE()
            // ---- stage 3: psum = k2 ----
            {
                float4 x4[2];
#pragma unroll
                for (int hh = 0; hh < 2; ++hh) {
                    const int ci = c8 * 2 + hh;
                    const float4 k0 = K4(smA, 0, ci);
                    const float4 p  = PS2SUM(smA, ci);
                    float4 acc; F4MUL(acc, A31, k0) F4FMA(acc, A32, p)
                    float4 xx = Y4(smA, ci); F4FMA(xx, dtcS, acc)
                    x4[hh] = xx;
                }
                if (t < 32) {
                    const int s_ = t >> 4;
                    const int ci_ = t & 15;
                    reinterpret_cast<float4*>(s_k[s_][1])[ci_] = PS2SUM(s_, ci_);
                }
                L0_FMA_STORE(x4)
            }
            FEVAL_BCDE()
            // ---- stage 4: psum = k3 ----
            {
                float4 x4[2];
#pragma unroll
                for (int hh = 0; hh < 2; ++hh) {
                    const int ci = c8 * 2 + hh;
                    const float4 k0  = K4(smA, 0, ci);
                    const float4 k1v = K4(smA, 1, ci);
                    const float4 p   = PS2SUM(smA, ci);
                    float4 acc; F4MUL(acc, A41, k0) F4FMA(acc, A42, k1v) F4FMA(acc, A43, p)
                    float4 xx = Y4(smA, ci); F4FMA(xx, dtcS, acc)
                    x4[hh] = xx;
                }
                if (t < 32) {
                    const int s_ = t >> 4;
                    const int ci_ = t & 15;
                    reinterpret_cast<float4*>(s_k[s_][2])[ci_] = PS2SUM(s_, ci_);
                }
                L0_FMA_STORE(x4)
            }
            FEVAL_BCDE()
            // ---- stage 5: psum = k4 ----
            {
                float4 x4[2];
#pragma unroll
                for (int hh = 0; hh < 2; ++hh) {
                    const int ci = c8 * 2 + hh;
                    const float4 k0  = K4(smA, 0, ci);
                    const float4 k1v = K4(smA, 1, ci);
                    const float4 k2v = K4(smA, 2, ci);
                    const float4 p   = PS2SUM(smA, ci);
                    float4 acc; F4MUL(acc, A51, k0) F4FMA(acc, A52, k1v)
                    F4FMA(acc, A53, k2v) F4FMA(acc, A54, p)
                    float4 xx = Y4(smA, ci); F4FMA(xx, dtcS, acc)
                    x4[hh] = xx;
                }
                if (t < 32) {
                    const int s_ = t >> 4;
                    const int ci_ = t & 15;
                    reinterpret_cast<float4*>(s_k[s_][3])[ci_] = PS2SUM(s_, ci_);
                }
                L0_FMA_STORE(x4)
            }
            FEVAL_BCDE()
            // ---- stage 6: psum = k5 ----
            {
                float4 x4[2];
#pragma unroll
                for (int hh = 0; hh < 2; ++hh) {
                    const int ci = c8 * 2 + hh;
                    const float4 k0  = K4(smA, 0, ci);
                    const float4 k1v = K4(smA, 1, ci);
                    const float4 k2v = K4(smA, 2, ci);
                    const float4 k3v = K4(smA, 3, ci);
                    const float4 p   = PS2SUM(smA, ci);
                    float4 acc; F4MUL(acc, A61, k0) F4FMA(acc, A62, k1v) F4FMA(acc, A63, k2v)
                    F4FMA(acc, A64, k3v) F4FMA(acc, A65, p)
                    float4 xx = Y4(smA, ci); F4FMA(xx, dtcS, acc)
                    x4[hh] = xx;
                }
                if (t < 32) {
                    const int s_ = t >> 4;
                    const int ci_ = t & 15;
                    reinterpret_cast<float4*>(s_k[s_][4])[ci_] = PS2SUM(s_, ci_);
                }
                L0_FMA_STORE(x4)
            }
            FEVAL_BCDE()
            // ---- stage 7: x = y_new (B-combo); psum = k6; also materialize y_new ----
            {
                float4 x4[2];
#pragma unroll
                for (int hh = 0; hh < 2; ++hh) {
                    const int ci = c8 * 2 + hh;
                    const float4 k0  = K4(smA, 0, ci);
                    const float4 k1v = K4(smA, 1, ci);
                    const float4 k2v = K4(smA, 2, ci);
                    const float4 k3v = K4(smA, 3, ci);
                    const float4 k4v = K4(smA, 4, ci);
                    const float4 p   = PS2SUM(smA, ci);
                    float4 acc; F4MUL(acc, B1c, k0) F4FMA(acc, B2c, k1v) F4FMA(acc, B3c, k2v)
                    F4FMA(acc, B4c, k3v) F4FMA(acc, B5c, k4v) F4FMA(acc, B6c, p)
                    float4 xx = Y4(smA, ci); F4FMA(xx, dtcS, acc)
                    x4[hh] = xx;
                }
                if (t < 32) {
                    const int s_ = t >> 4;
                    const int ci_ = t & 15;
                    const float dtS = (s_ == 0) ? dtc0 : dtc1;
                    const float4 p = PS2SUM(s_, ci_);
                    reinterpret_cast<float4*>(s_k[s_][5])[ci_] = p;   // k6
                    const float4 k0  = K4(s_, 0, ci_);
                    const float4 k1v = K4(s_, 1, ci_);
                    const float4 k2v = K4(s_, 2, ci_);
                    const float4 k3v = K4(s_, 3, ci_);
                    const float4 k4v = K4(s_, 4, ci_);
                    float4 acc; F4MUL(acc, B1c, k0) F4FMA(acc, B2c, k1v) F4FMA(acc, B3c, k2v)
                    F4FMA(acc, B4c, k3v) F4FMA(acc, B5c, k4v) F4FMA(acc, B6c, p)
                    float4 yn = Y4(s_, ci_); F4FMA(yn, dtS, acc)
                    reinterpret_cast<float4*>(s_ynew[s_])[ci_] = yn;
                }
                L0_FMA_STORE(x4)
            }
            FEVAL_BCDE()

            // ---- error estimate (k7 = psum of s_ps2) ----
            if (t < 128) {
                const int s_ = t >> 6;
                const int d_ = t & 63;
                const float dtS = (s_ == 0) ? dtc0 : dtc1;
                const float kv7 = ((s_ps2[s_][0][d_] + s_ps2[s_][1][d_]) + (s_ps2[s_][2][d_] + s_ps2[s_][3][d_]))
                                + ((s_ps2[s_][4][d_] + s_ps2[s_][5][d_]) + (s_ps2[s_][6][d_] + s_ps2[s_][7][d_]));
                const float e = dtS * (E1c * s_k[s_][0][d_] + E2c * s_k[s_][1][d_]
                                     + E3c * s_k[s_][2][d_] + E4c * s_k[s_][3][d_]
                                     + E5c * s_k[s_][4][d_] + E6c * s_k[s_][5][d_] + E7c * kv7);
                const float yv = s_y[s_][d_], ynv = s_ynew[s_][d_];
                const float sc = ATOLc + RTOLc * fmaxf(fabsf(yv), fabsf(ynv));
                const float rr2 = e / sc;
                float v = rr2 * rr2;
#pragma unroll
                for (int off = 32; off > 0; off >>= 1) v += __shfl_xor(v, off, 64);
                if (d_ == 0) s_err[s_] = v;
            }
            __syncthreads();

            // ---- controller (replicated) + masked commit (incl. FSAL k1 <- k7) ----
            const float en0 = sqrtf(s_err[0] * (1.0f / DATA));
            const float en1 = sqrtf(s_err[1] * (1.0f / DATA));
            const bool acc0 = en0 <= 1.0f, acc1 = en1 <= 1.0f;
            float f0 = fminf(fmaxf(SAFETYc * powf(fmaxf(en0, 1e-10f), -0.2f), FMINc), FMAXc);
            float f1 = fminf(fmaxf(SAFETYc * powf(fmaxf(en1, 1e-10f), -0.2f), FMINc), FMAXc);
            const bool step0 = acc0 && !done0, step1 = acc1 && !done1;
            if (t < 32) {
                const int s_ = t >> 4;
                const int ci_ = t & 15;
                const bool st = (s_ == 0) ? step0 : step1;
                if (st) {
                    reinterpret_cast<float4*>(s_y[s_])[ci_] =
                        reinterpret_cast<const float4*>(s_ynew[s_])[ci_];
                    reinterpret_cast<float4*>(s_k[s_][0])[ci_] = PS2SUM(s_, ci_);  // k1 = k7
                }
            }
            if (step0) tc0 += dtc0;
            if (step1) tc1 += dtc1;
            dtv0 = done0 ? dtv0 : dtc0 * f0;
            dtv1 = done1 ? dtv1 : dtc1 * f1;
            __syncthreads();
        }

        if (t < 128) {
            const int s_ = t >> 6;
            const int d_ = t & 63;
            out[(size_t)(b * NSAMP + s_) * TPTS * DATA + (size_t)(iv + 1) * DATA + d_] = s_y[s_][d_];
        }
        // no barrier needed: next substep only broadcast-reads s_y (no writes before its barriers)
    }
}

extern "C" void kernel_launch(void* const* d_in, const int* in_sizes, int n_in,
                              void* d_out, int out_size, void* d_ws, size_t ws_size,
                              hipStream_t stream)
{
    const float* ts = (const float*)d_in[0];
    const float* y0 = (const float*)d_in[1];
    const float* W0 = (const float*)d_in[2];
    const float* b0 = (const float*)d_in[3];
    const float* W1 = (const float*)d_in[4];
    const float* b1 = (const float*)d_in[5];
    const float* W2 = (const float*)d_in[6];
    const float* b2 = (const float*)d_in[7];
    float* out = (float*)d_out;

    ode_kernel<<<NBLK, NTHR, 0, stream>>>(ts, y0, W0, b0, W1, b1, W2, b2, out);
}